// Round 4
// baseline (247.040 us; speedup 1.0000x reference)
//
#include <hip/hip_runtime.h>
#include <cstdint>
#include <cstddef>

// One wave (64 lanes) per batch; 4 waves (4 batches) per 256-thread block to
// escape the ~8 workgroup-slot/CU cap seen at 1-wave blocks (Occupancy 24%).
// Each wave uses a PRIVATE LDS slice; cross-lane LDS traffic is ordered with
// __syncthreads() exactly as in the verified R2 kernel (all waves execute the
// same barrier sequence). Sinkhorn runs in diagonal form
// x = diag(u) * X0 * diag(v); dots use packed f32 FMA with an accumulator
// grouping that reproduces R2's summation order bitwise. Greedy unique-argmax
// is R2 verbatim (u64 key, __shfl_xor butterfly — verified primitives only).

typedef float f2 __attribute__((ext_vector_type(2)));

#define TROW 68   // staging row stride (floats); 16B aligned, conflict-free

__device__ __forceinline__ f2 fma2(f2 a, f2 b, f2 c) {
#if defined(__has_builtin) && __has_builtin(__builtin_elementwise_fma)
    return __builtin_elementwise_fma(a, b, c);
#else
    f2 r; r.x = __builtin_fmaf(a.x, b.x, c.x); r.y = __builtin_fmaf(a.y, b.y, c.y);
    return r;
#endif
}

#define RESCAN(G)                                                            \
  {                                                                          \
    float nv_ = -__builtin_inff(); int na_ = (G) * 8;                        \
    _Pragma("unroll")                                                        \
    for (int k_ = 0; k_ < 8; ++k_) {                                         \
      const int idx_ = (G) * 8 + k_;                                         \
      float vk_ = ((rowmask >> idx_) & 1ull) ? col[idx_]                     \
                                             : -__builtin_inff();            \
      if (vk_ > nv_) { nv_ = vk_; na_ = idx_; }                              \
    }                                                                        \
    gv[(G)] = nv_; ga[(G)] = na_;                                            \
  }

__global__ void __launch_bounds__(256, 3)
sinkhorn_perm_kernel(const float* __restrict__ logits,
                     const float* __restrict__ ptemp,
                     float* __restrict__ out, int B)
{
    const int wid  = threadIdx.x >> 6;
    const int lane = threadIdx.x & 63;
    int b = blockIdx.x * 4 + wid;
    if (b >= B) b = B - 1;            // clamp (keeps all waves in barriers)

    __shared__ float lds[4][16 * TROW];   // 4352 B per wave slice
    float* W = &lds[wid][0];

    const float* base = logits + (size_t)b * 4096;

    const float T    = ptemp[0] + 1e-6f;
    const float invT = 1.0f / T;          // IEEE divide (one-time)

    // ---- load row `lane`, scale by invT (pairs kept adjacent) ---------
    f2 row2[32];
    {
        const float4* rp = (const float4*)(base + lane * 64);
        #pragma unroll
        for (int t = 0; t < 16; ++t) {
            float4 q = rp[t];
            row2[2*t+0].x = __fmul_rn(q.x, invT);
            row2[2*t+0].y = __fmul_rn(q.y, invT);
            row2[2*t+1].x = __fmul_rn(q.z, invT);
            row2[2*t+1].y = __fmul_rn(q.w, invT);
        }
    }

    // ---- global max over the 64x64 tile -------------------------------
    float mx = row2[0].x;
    #pragma unroll
    for (int i = 0; i < 32; ++i) { mx = fmaxf(mx, row2[i].x); mx = fmaxf(mx, row2[i].y); }
    #pragma unroll
    for (int w = 1; w <= 32; w <<= 1)
        mx = fmaxf(mx, __shfl_xor(mx, w, 64));

    // ---- x0 row copy: exp(scaled - mx) --------------------------------
    #pragma unroll
    for (int i = 0; i < 32; ++i) {
        row2[i].x = __expf(__fsub_rn(row2[i].x, mx));
        row2[i].y = __expf(__fsub_rn(row2[i].y, mx));
    }

    // ---- column copy via LDS transpose (barriered, as in R2) ----------
    float col[64];
    #pragma unroll
    for (int ch = 0; ch < 4; ++ch) {
        if ((lane >> 4) == ch) {
            float4* wp = (float4*)&W[(lane & 15) * TROW];
            #pragma unroll
            for (int t = 0; t < 16; ++t)
                wp[t] = make_float4(row2[2*t].x, row2[2*t].y, row2[2*t+1].x, row2[2*t+1].y);
        }
        __syncthreads();
        #pragma unroll
        for (int t = 0; t < 16; ++t)
            col[ch*16 + t] = W[t * TROW + lane];
        __syncthreads();
    }

    // ---- sinkhorn in diag(u) * X0 * diag(v) form ----------------------
    float u = 1.0f, v = 1.0f;
    for (int it = 0; it < 30; ++it) {
        // row phase: rs_i = row_i . v   (v broadcast via LDS float4 reads)
        W[lane] = v;
        __syncthreads();
        f2 A0 = {0.f, 0.f}, A1 = {0.f, 0.f};
        #pragma unroll
        for (int t = 0; t < 16; ++t) {
            float4 q = ((const float4*)W)[t];
            f2 qa = {q.x, q.y}, qb = {q.z, q.w};
            A0 = fma2(row2[2*t+0], qa, A0);
            A1 = fma2(row2[2*t+1], qb, A1);
        }
        float rs = __fadd_rn(__fadd_rn(A0.x, A0.y), __fadd_rn(A1.x, A1.y));
        u = u / __fadd_rn(__fmul_rn(u, rs), 1e-8f);   // IEEE divide
        __syncthreads();

        // col phase: cs_j = col_j . u  (updated u broadcast)
        W[lane] = u;
        __syncthreads();
        A0 = (f2){0.f, 0.f}; A1 = (f2){0.f, 0.f};
        #pragma unroll
        for (int t = 0; t < 16; ++t) {
            float4 q = ((const float4*)W)[t];
            f2 ca = {col[4*t+0], col[4*t+1]}, cb = {col[4*t+2], col[4*t+3]};
            f2 qa = {q.x, q.y},               qb = {q.z, q.w};
            A0 = fma2(ca, qa, A0);
            A1 = fma2(cb, qb, A1);
        }
        float cs = __fadd_rn(__fadd_rn(A0.x, A0.y), __fadd_rn(A1.x, A1.y));
        v = v / __fadd_rn(__fmul_rn(v, cs), 1e-8f);
        __syncthreads();
    }

    // ---- final scores: s[i][j] = (x0[i][j] * u_i) * v_j ----------------
    W[lane] = u;
    __syncthreads();
    #pragma unroll
    for (int t = 0; t < 16; ++t) {
        float4 q = ((const float4*)W)[t];
        col[4*t+0] = __fmul_rn(__fmul_rn(col[4*t+0], q.x), v);
        col[4*t+1] = __fmul_rn(__fmul_rn(col[4*t+1], q.y), v);
        col[4*t+2] = __fmul_rn(__fmul_rn(col[4*t+2], q.z), v);
        col[4*t+3] = __fmul_rn(__fmul_rn(col[4*t+3], q.w), v);
    }

    // ---- greedy unique argmax (R2 verbatim; matches stable argsort(-s)) -
    float gv[8]; int ga[8];
    #pragma unroll
    for (int g = 0; g < 8; ++g) {
        float bv2 = col[8*g]; int ba2 = 8*g;
        #pragma unroll
        for (int k = 1; k < 8; ++k)
            if (col[8*g+k] > bv2) { bv2 = col[8*g+k]; ba2 = 8*g+k; }
        gv[g] = bv2; ga[g] = ba2;
    }

    unsigned long long rowmask = ~0ull;   // wave-uniform (SGPR pair)
    int  mycol = 0;
    bool done  = false;

    for (int step = 0; step < 64; ++step) {
        // per-lane best over 8 groups (ascending + strict '>' => min idx on tie)
        float bv = gv[0]; int ba = ga[0];
        #pragma unroll
        for (int g2 = 1; g2 < 8; ++g2)
            if (gv[g2] > bv) { bv = gv[g2]; ba = ga[g2]; }

        // pack (value desc, flat idx asc) into one u64 key
        unsigned flat = ((unsigned)ba << 6) | (unsigned)lane;   // r*64 + c
        unsigned long long key =
            ((unsigned long long)__float_as_uint(bv) << 12) | (4095u - flat);
        if (done) key = 0ull;

        #pragma unroll
        for (int m = 1; m <= 32; m <<= 1) {
            unsigned long long o = __shfl_xor(key, m, 64);
            if (o > key) key = o;
        }

        unsigned wflat = 4095u - (unsigned)(key & 4095ull);
        int r = __builtin_amdgcn_readfirstlane((int)(wflat >> 6));  // uniform
        int c = (int)(wflat & 63u);

        if (lane == r) mycol = c;       // lane r owns output row r
        if (lane == c) done  = true;    // retire column c
        rowmask &= ~(1ull << r);        // retire row r (scalar)

        // rescan only the 8-row group containing r (r>>3 wave-uniform)
        switch (r >> 3) {
            case 0: RESCAN(0) break;
            case 1: RESCAN(1) break;
            case 2: RESCAN(2) break;
            case 3: RESCAN(3) break;
            case 4: RESCAN(4) break;
            case 5: RESCAN(5) break;
            case 6: RESCAN(6) break;
            case 7: RESCAN(7) break;
        }
    }

    // ---- write hard permutation row (lane i -> row i) -----------------
    float* orow = out + (size_t)b * 4096 + lane * 64;
    #pragma unroll
    for (int t = 0; t < 16; ++t) {
        float4 q;
        q.x = (4*t+0 == mycol) ? 1.0f : 0.0f;
        q.y = (4*t+1 == mycol) ? 1.0f : 0.0f;
        q.z = (4*t+2 == mycol) ? 1.0f : 0.0f;
        q.w = (4*t+3 == mycol) ? 1.0f : 0.0f;
        ((float4*)orow)[t] = q;
    }
}

extern "C" void kernel_launch(void* const* d_in, const int* in_sizes, int n_in,
                              void* d_out, int out_size, void* d_ws, size_t ws_size,
                              hipStream_t stream) {
    const float* logits = (const float*)d_in[0];
    const float* ptemp  = (const float*)d_in[1];
    float* out = (float*)d_out;
    const int B = in_sizes[0] / 4096;   // 64*64 elements per batch
    sinkhorn_perm_kernel<<<(B + 3) / 4, 256, 0, stream>>>(logits, ptemp, out, B);
}

// Round 5
// 221.121 us; speedup vs baseline: 1.1172x; 1.1172x over previous
//
#include <hip/hip_runtime.h>
#include <cstdint>
#include <cstddef>

// One wave (64 lanes) per batch (B=4096, N=K=64). ZERO __shared__ usage:
// the per-CU DS pipe (1 per CU, shared by 4 SIMDs) was the R2/R4 bottleneck
// (~18k DS-cycles/wave of broadcast reads). Sinkhorn broadcasts now go
// through v_readlane (VALU pipe, 4/CU); the column copy comes from a second
// coalesced global read with a bitwise-identical exp sequence (R1-verified).
// Greedy unique-argmax retires TWO assignments per wave reduction via a
// top-2 float butterfly + ballot fast path (provably order-equivalent to
// stable argsort greedy); any value-tie ambiguity falls back to the
// R2-verified u64-key single-retirement butterfly.

__device__ __forceinline__ float rl(float x, int lane) {
    return __uint_as_float((unsigned)__builtin_amdgcn_readlane((int)__float_as_uint(x), lane));
}

#define RESCAN(G)                                                            \
  {                                                                          \
    float nv_ = -__builtin_inff(); int na_ = (G) * 8;                        \
    _Pragma("unroll")                                                        \
    for (int k_ = 0; k_ < 8; ++k_) {                                         \
      const int idx_ = (G) * 8 + k_;                                         \
      float vk_ = ((rowmask >> idx_) & 1ull) ? col[idx_]                     \
                                             : -__builtin_inff();            \
      if (vk_ > nv_) { nv_ = vk_; na_ = idx_; }                              \
    }                                                                        \
    gv[(G)] = nv_; ga[(G)] = na_;                                            \
  }

#define RESCAN_SWITCH(RG)                                                    \
    switch (RG) {                                                            \
        case 0: RESCAN(0) break;                                             \
        case 1: RESCAN(1) break;                                             \
        case 2: RESCAN(2) break;                                             \
        case 3: RESCAN(3) break;                                             \
        case 4: RESCAN(4) break;                                             \
        case 5: RESCAN(5) break;                                             \
        case 6: RESCAN(6) break;                                             \
        case 7: RESCAN(7) break;                                             \
    }

__global__ void __launch_bounds__(64, 2)
sinkhorn_perm_kernel(const float* __restrict__ logits,
                     const float* __restrict__ ptemp,
                     float* __restrict__ out)
{
    const int b    = blockIdx.x;
    const int lane = threadIdx.x;
    const float* base = logits + (size_t)b * 4096;

    const float T    = ptemp[0] + 1e-6f;
    const float invT = 1.0f / T;          // IEEE divide (one-time)

    // ---- load row `lane`, scale by invT -------------------------------
    float row[64];
    {
        const float4* rp = (const float4*)(base + lane * 64);
        #pragma unroll
        for (int t = 0; t < 16; ++t) {
            float4 q = rp[t];
            row[4*t+0] = __fmul_rn(q.x, invT);
            row[4*t+1] = __fmul_rn(q.y, invT);
            row[4*t+2] = __fmul_rn(q.z, invT);
            row[4*t+3] = __fmul_rn(q.w, invT);
        }
    }

    // ---- global max over the 64x64 tile -------------------------------
    float mx = row[0];
    #pragma unroll
    for (int i = 1; i < 64; ++i) mx = fmaxf(mx, row[i]);
    #pragma unroll
    for (int w = 1; w <= 32; w <<= 1)
        mx = fmaxf(mx, __shfl_xor(mx, w, 64));

    // ---- x0 row copy: exp(scaled - mx) --------------------------------
    #pragma unroll
    for (int i = 0; i < 64; ++i)
        row[i] = __expf(__fsub_rn(row[i], mx));

    // ---- x0 column copy: coalesced global re-read, identical op seq ---
    float col[64];
    #pragma unroll
    for (int i = 0; i < 64; ++i) {
        float raw = base[i * 64 + lane];
        col[i] = __expf(__fsub_rn(__fmul_rn(raw, invT), mx));
    }

    // ---- sinkhorn in diag(u) * X0 * diag(v) form (VALU broadcasts) ----
    float u = 1.0f, v = 1.0f;
    for (int it = 0; it < 30; ++it) {
        // row phase: rs_i = row_i . v  (v_j broadcast via readlane)
        float a0 = 0.f, a1 = 0.f, a2 = 0.f, a3 = 0.f;
        #pragma unroll
        for (int j = 0; j < 64; j += 4) {
            a0 = __builtin_fmaf(row[j+0], rl(v, j+0), a0);
            a1 = __builtin_fmaf(row[j+1], rl(v, j+1), a1);
            a2 = __builtin_fmaf(row[j+2], rl(v, j+2), a2);
            a3 = __builtin_fmaf(row[j+3], rl(v, j+3), a3);
        }
        float rs = __fadd_rn(__fadd_rn(a0, a1), __fadd_rn(a2, a3));
        u = u / __fadd_rn(__fmul_rn(u, rs), 1e-8f);   // IEEE divide

        // col phase: cs_j = col_j . u  (updated u broadcast)
        a0 = a1 = a2 = a3 = 0.f;
        #pragma unroll
        for (int i = 0; i < 64; i += 4) {
            a0 = __builtin_fmaf(col[i+0], rl(u, i+0), a0);
            a1 = __builtin_fmaf(col[i+1], rl(u, i+1), a1);
            a2 = __builtin_fmaf(col[i+2], rl(u, i+2), a2);
            a3 = __builtin_fmaf(col[i+3], rl(u, i+3), a3);
        }
        float cs = __fadd_rn(__fadd_rn(a0, a1), __fadd_rn(a2, a3));
        v = v / __fadd_rn(__fmul_rn(v, cs), 1e-8f);
    }

    // ---- final scores: s[i][j] = (x0[i][j] * u_i) * v_j ---------------
    #pragma unroll
    for (int i = 0; i < 64; ++i)
        col[i] = __fmul_rn(__fmul_rn(col[i], rl(u, i)), v);

    // ---- greedy unique argmax (top-2 fast path + verified fallback) ---
    unsigned long long rowmask = ~0ull;   // wave-uniform (SGPR pair)
    float gv[8]; int ga[8];
    #pragma unroll
    for (int g = 0; g < 8; ++g) RESCAN(g)

    int  mycol   = 0;
    bool done    = false;
    int  retired = 0;
    const float NEGINF = -__builtin_inff();

    while (retired < 64) {
        // per-lane best over 8 groups (ascending + strict '>' => min row on tie)
        float bv = gv[0]; int ba = ga[0];
        #pragma unroll
        for (int g2 = 1; g2 < 8; ++g2)
            if (gv[g2] > bv) { bv = gv[g2]; ba = ga[g2]; }
        float mybv = done ? NEGINF : bv;

        // wave-wide top-2 values (butterfly; disjoint-group merge each stage)
        float m1 = mybv, m2 = NEGINF;
        #pragma unroll
        for (int m = 1; m <= 32; m <<= 1) {
            float o1 = __shfl_xor(m1, m, 64);
            float o2 = __shfl_xor(m2, m, 64);
            float hi = fmaxf(m1, o1);
            float lo = fminf(m1, o1);
            m1 = hi;
            m2 = fmaxf(lo, fmaxf(m2, o2));
        }

        int r1, c1, r2 = -1, c2 = -1;
        bool two = false;
        unsigned long long t1 = __ballot(mybv == m1);   // wave-uniform
        bool fast1 = (__popcll(t1) == 1) && (m2 > NEGINF);

        if (fast1) {
            c1 = (int)__builtin_ctzll(t1);
            r1 = __builtin_amdgcn_readlane(ba, c1);
            unsigned long long t2 = __ballot(mybv == m2);
            if (__popcll(t2) == 1) {
                c2 = (int)__builtin_ctzll(t2);
                r2 = __builtin_amdgcn_readlane(ba, c2);
                two = (r2 != r1);
            }
        } else {
            // fallback: R2-verified u64-key single retirement
            unsigned flat = ((unsigned)ba << 6) | (unsigned)lane;   // r*64 + c
            unsigned long long key =
                ((unsigned long long)__float_as_uint(bv) << 12) | (4095u - flat);
            if (done) key = 0ull;
            #pragma unroll
            for (int m = 1; m <= 32; m <<= 1) {
                unsigned long long o = __shfl_xor(key, m, 64);
                if (o > key) key = o;
            }
            unsigned wflat = 4095u - (unsigned)(key & 4095ull);
            r1 = __builtin_amdgcn_readfirstlane((int)(wflat >> 6));
            c1 = (int)(wflat & 63u);
        }

        // retire (r1,c1) [and (r2,c2)]
        if (lane == r1) mycol = c1;
        if (lane == c1) done  = true;
        rowmask &= ~(1ull << r1);
        retired++;
        if (two) {
            if (lane == r2) mycol = c2;
            if (lane == c2) done  = true;
            rowmask &= ~(1ull << r2);
            retired++;
        }

        // rescan affected group(s); (r>>3) is wave-uniform
        RESCAN_SWITCH(r1 >> 3)
        if (two && ((r2 >> 3) != (r1 >> 3))) {
            RESCAN_SWITCH(r2 >> 3)
        }
    }

    // ---- write hard permutation row (lane i -> row i) -----------------
    float* orow = out + (size_t)b * 4096 + lane * 64;
    #pragma unroll
    for (int t = 0; t < 16; ++t) {
        float4 q;
        q.x = (4*t+0 == mycol) ? 1.0f : 0.0f;
        q.y = (4*t+1 == mycol) ? 1.0f : 0.0f;
        q.z = (4*t+2 == mycol) ? 1.0f : 0.0f;
        q.w = (4*t+3 == mycol) ? 1.0f : 0.0f;
        ((float4*)orow)[t] = q;
    }
}

extern "C" void kernel_launch(void* const* d_in, const int* in_sizes, int n_in,
                              void* d_out, int out_size, void* d_ws, size_t ws_size,
                              hipStream_t stream) {
    const float* logits = (const float*)d_in[0];
    const float* ptemp  = (const float*)d_in[1];
    float* out = (float*)d_out;
    const int B = in_sizes[0] / 4096;   // 64*64 elements per batch
    sinkhorn_perm_kernel<<<B, 64, 0, stream>>>(logits, ptemp, out);
}

// Round 6
// 220.520 us; speedup vs baseline: 1.1203x; 1.0027x over previous
//
#include <hip/hip_runtime.h>
#include <cstdint>
#include <cstddef>

// One wave (64 lanes) per batch (B=4096, N=K=64). Zero __shared__.
// R6 change vs R5 (verified): give the register allocator the full arch-VGPR
// budget (amdgpu_waves_per_eu(1) + launch_bounds(64)) so row[64]+col[64] live
// entirely in arch VGPRs (R5's VGPR_Count=100 forced AGPR/remat traffic that
// ~doubled VALU instructions). Sinkhorn dots use the R4-verified pk_fma
// pairing (bitwise-identical summation order). Greedy phase is R5 verbatim.

typedef float f2 __attribute__((ext_vector_type(2)));

__device__ __forceinline__ float rl(float x, int lane) {
    return __uint_as_float((unsigned)__builtin_amdgcn_readlane((int)__float_as_uint(x), lane));
}

__device__ __forceinline__ f2 fma2(f2 a, f2 b, f2 c) {
#if defined(__has_builtin) && __has_builtin(__builtin_elementwise_fma)
    return __builtin_elementwise_fma(a, b, c);
#else
    f2 r; r.x = __builtin_fmaf(a.x, b.x, c.x); r.y = __builtin_fmaf(a.y, b.y, c.y);
    return r;
#endif
}

#define RESCAN(G)                                                            \
  {                                                                          \
    float nv_ = -__builtin_inff(); int na_ = (G) * 8;                        \
    _Pragma("unroll")                                                        \
    for (int k_ = 0; k_ < 8; ++k_) {                                         \
      const int idx_ = (G) * 8 + k_;                                         \
      float vk_ = ((rowmask >> idx_) & 1ull) ? col[idx_]                     \
                                             : -__builtin_inff();            \
      if (vk_ > nv_) { nv_ = vk_; na_ = idx_; }                              \
    }                                                                        \
    gv[(G)] = nv_; ga[(G)] = na_;                                            \
  }

#define RESCAN_SWITCH(RG)                                                    \
    switch (RG) {                                                            \
        case 0: RESCAN(0) break;                                             \
        case 1: RESCAN(1) break;                                             \
        case 2: RESCAN(2) break;                                             \
        case 3: RESCAN(3) break;                                             \
        case 4: RESCAN(4) break;                                             \
        case 5: RESCAN(5) break;                                             \
        case 6: RESCAN(6) break;                                             \
        case 7: RESCAN(7) break;                                             \
    }

__global__ void __launch_bounds__(64)
__attribute__((amdgpu_waves_per_eu(1)))
sinkhorn_perm_kernel(const float* __restrict__ logits,
                     const float* __restrict__ ptemp,
                     float* __restrict__ out)
{
    const int b    = blockIdx.x;
    const int lane = threadIdx.x;
    const float* base = logits + (size_t)b * 4096;

    const float T    = ptemp[0] + 1e-6f;
    const float invT = 1.0f / T;          // IEEE divide (one-time)

    // ---- load row `lane`, scale by invT; pairs (4t,4t+1),(4t+2,4t+3) --
    f2 row2[32];
    {
        const float4* rp = (const float4*)(base + lane * 64);
        #pragma unroll
        for (int t = 0; t < 16; ++t) {
            float4 q = rp[t];
            row2[2*t+0].x = __fmul_rn(q.x, invT);
            row2[2*t+0].y = __fmul_rn(q.y, invT);
            row2[2*t+1].x = __fmul_rn(q.z, invT);
            row2[2*t+1].y = __fmul_rn(q.w, invT);
        }
    }

    // ---- global max over the 64x64 tile -------------------------------
    float mx = row2[0].x;
    #pragma unroll
    for (int i = 0; i < 32; ++i) { mx = fmaxf(mx, row2[i].x); mx = fmaxf(mx, row2[i].y); }
    #pragma unroll
    for (int w = 1; w <= 32; w <<= 1)
        mx = fmaxf(mx, __shfl_xor(mx, w, 64));

    // ---- x0 row copy: exp(scaled - mx) --------------------------------
    #pragma unroll
    for (int i = 0; i < 32; ++i) {
        row2[i].x = __expf(__fsub_rn(row2[i].x, mx));
        row2[i].y = __expf(__fsub_rn(row2[i].y, mx));
    }

    // ---- x0 column copy: coalesced global re-read, identical op seq ---
    float col[64];
    #pragma unroll
    for (int i = 0; i < 64; ++i) {
        float raw = base[i * 64 + lane];
        col[i] = __expf(__fsub_rn(__fmul_rn(raw, invT), mx));
    }

    // ---- sinkhorn in diag(u) * X0 * diag(v) form (VALU broadcasts) ----
    // pk_fma pairing: A0.x: j%4==0, A0.y: j%4==1, A1.x: j%4==2, A1.y: j%4==3
    // => rs = (A0.x+A0.y)+(A1.x+A1.y) == R5's (a0+a1)+(a2+a3) bitwise.
    float u = 1.0f, v = 1.0f;
    for (int it = 0; it < 30; ++it) {
        // row phase: rs_i = row_i . v  (v_j broadcast via readlane pairs)
        f2 A0 = {0.f, 0.f}, A1 = {0.f, 0.f};
        #pragma unroll
        for (int t = 0; t < 16; ++t) {
            f2 qa = { rl(v, 4*t+0), rl(v, 4*t+1) };
            f2 qb = { rl(v, 4*t+2), rl(v, 4*t+3) };
            A0 = fma2(row2[2*t+0], qa, A0);
            A1 = fma2(row2[2*t+1], qb, A1);
        }
        float rs = __fadd_rn(__fadd_rn(A0.x, A0.y), __fadd_rn(A1.x, A1.y));
        u = u / __fadd_rn(__fmul_rn(u, rs), 1e-8f);   // IEEE divide

        // col phase: cs_j = col_j . u  (updated u broadcast)
        A0 = (f2){0.f, 0.f}; A1 = (f2){0.f, 0.f};
        #pragma unroll
        for (int t = 0; t < 16; ++t) {
            f2 ca = { col[4*t+0], col[4*t+1] };
            f2 cb = { col[4*t+2], col[4*t+3] };
            f2 qa = { rl(u, 4*t+0), rl(u, 4*t+1) };
            f2 qb = { rl(u, 4*t+2), rl(u, 4*t+3) };
            A0 = fma2(ca, qa, A0);
            A1 = fma2(cb, qb, A1);
        }
        float cs = __fadd_rn(__fadd_rn(A0.x, A0.y), __fadd_rn(A1.x, A1.y));
        v = v / __fadd_rn(__fmul_rn(v, cs), 1e-8f);
    }

    // ---- final scores: s[i][j] = (x0[i][j] * u_i) * v_j ---------------
    #pragma unroll
    for (int i = 0; i < 64; ++i)
        col[i] = __fmul_rn(__fmul_rn(col[i], rl(u, i)), v);

    // ---- greedy unique argmax (R5 verbatim: top-2 + verified fallback) -
    unsigned long long rowmask = ~0ull;   // wave-uniform (SGPR pair)
    float gv[8]; int ga[8];
    #pragma unroll
    for (int g = 0; g < 8; ++g) RESCAN(g)

    int  mycol   = 0;
    bool done    = false;
    int  retired = 0;
    const float NEGINF = -__builtin_inff();

    while (retired < 64) {
        // per-lane best over 8 groups (ascending + strict '>' => min row on tie)
        float bv = gv[0]; int ba = ga[0];
        #pragma unroll
        for (int g2 = 1; g2 < 8; ++g2)
            if (gv[g2] > bv) { bv = gv[g2]; ba = ga[g2]; }
        float mybv = done ? NEGINF : bv;

        // wave-wide top-2 values (butterfly; disjoint-group merge each stage)
        float m1 = mybv, m2 = NEGINF;
        #pragma unroll
        for (int m = 1; m <= 32; m <<= 1) {
            float o1 = __shfl_xor(m1, m, 64);
            float o2 = __shfl_xor(m2, m, 64);
            float hi = fmaxf(m1, o1);
            float lo = fminf(m1, o1);
            m1 = hi;
            m2 = fmaxf(lo, fmaxf(m2, o2));
        }

        int r1, c1, r2 = -1, c2 = -1;
        bool two = false;
        unsigned long long t1 = __ballot(mybv == m1);   // wave-uniform
        bool fast1 = (__popcll(t1) == 1) && (m2 > NEGINF);

        if (fast1) {
            c1 = (int)__builtin_ctzll(t1);
            r1 = __builtin_amdgcn_readlane(ba, c1);
            unsigned long long t2 = __ballot(mybv == m2);
            if (__popcll(t2) == 1) {
                c2 = (int)__builtin_ctzll(t2);
                r2 = __builtin_amdgcn_readlane(ba, c2);
                two = (r2 != r1);
            }
        } else {
            // fallback: R2-verified u64-key single retirement
            unsigned flat = ((unsigned)ba << 6) | (unsigned)lane;   // r*64 + c
            unsigned long long key =
                ((unsigned long long)__float_as_uint(bv) << 12) | (4095u - flat);
            if (done) key = 0ull;
            #pragma unroll
            for (int m = 1; m <= 32; m <<= 1) {
                unsigned long long o = __shfl_xor(key, m, 64);
                if (o > key) key = o;
            }
            unsigned wflat = 4095u - (unsigned)(key & 4095ull);
            r1 = __builtin_amdgcn_readfirstlane((int)(wflat >> 6));
            c1 = (int)(wflat & 63u);
        }

        // retire (r1,c1) [and (r2,c2)]
        if (lane == r1) mycol = c1;
        if (lane == c1) done  = true;
        rowmask &= ~(1ull << r1);
        retired++;
        if (two) {
            if (lane == r2) mycol = c2;
            if (lane == c2) done  = true;
            rowmask &= ~(1ull << r2);
            retired++;
        }

        // rescan affected group(s); (r>>3) is wave-uniform
        RESCAN_SWITCH(r1 >> 3)
        if (two && ((r2 >> 3) != (r1 >> 3))) {
            RESCAN_SWITCH(r2 >> 3)
        }
    }

    // ---- write hard permutation row (lane i -> row i) -----------------
    float* orow = out + (size_t)b * 4096 + lane * 64;
    #pragma unroll
    for (int t = 0; t < 16; ++t) {
        float4 q;
        q.x = (4*t+0 == mycol) ? 1.0f : 0.0f;
        q.y = (4*t+1 == mycol) ? 1.0f : 0.0f;
        q.z = (4*t+2 == mycol) ? 1.0f : 0.0f;
        q.w = (4*t+3 == mycol) ? 1.0f : 0.0f;
        ((float4*)orow)[t] = q;
    }
}

extern "C" void kernel_launch(void* const* d_in, const int* in_sizes, int n_in,
                              void* d_out, int out_size, void* d_ws, size_t ws_size,
                              hipStream_t stream) {
    const float* logits = (const float*)d_in[0];
    const float* ptemp  = (const float*)d_in[1];
    float* out = (float*)d_out;
    const int B = in_sizes[0] / 4096;   // 64*64 elements per batch
    sinkhorn_perm_kernel<<<B, 64, 0, stream>>>(logits, ptemp, out);
}